// Round 1
// baseline (9343.288 us; speedup 1.0000x reference)
//
#include <hip/hip_runtime.h>
#include <hip/hip_cooperative_groups.h>

namespace cg = cooperative_groups;

#define NN 4096
#define QQ 2048
#define LDM 8192
#define GOFF 16384  // float offset of G inside ws

// ---------- helpers ----------
__device__ __forceinline__ float erfinv_f(float x){
  float w = -logf((1.0f - x)*(1.0f + x));
  float p;
  if (w < 5.0f) {
    w = w - 2.5f;
    p = 2.81022636e-08f;
    p = fmaf(p, w, 3.43273939e-07f);
    p = fmaf(p, w, -3.5233877e-06f);
    p = fmaf(p, w, -4.39150654e-06f);
    p = fmaf(p, w, 0.00021858087f);
    p = fmaf(p, w, -0.00125372503f);
    p = fmaf(p, w, -0.00417768164f);
    p = fmaf(p, w, 0.246640727f);
    p = fmaf(p, w, 1.50140941f);
  } else {
    w = sqrtf(w) - 3.0f;
    p = -0.000200214257f;
    p = fmaf(p, w, 0.000100950558f);
    p = fmaf(p, w, 0.00134934322f);
    p = fmaf(p, w, -0.00367342844f);
    p = fmaf(p, w, 0.00573950773f);
    p = fmaf(p, w, -0.0076224613f);
    p = fmaf(p, w, 0.00943887047f);
    p = fmaf(p, w, 1.00167406f);
    p = fmaf(p, w, 2.83297682f);
  }
  return p * x;
}

__device__ __forceinline__ float wave_red(float v){
  #pragma unroll
  for (int o = 32; o > 0; o >>= 1) v += __shfl_down(v, o, 64);
  return v;
}

// One cooperative kernel for the whole pipeline. Phases separated by grid.sync().
// LDS: single 64 KB buffer unioned across phases.
// Panel (block 0) is fully in-place in sm:
//   factored tile col-major in LOWER slots sm[col*128+row] (row>=col),
//   W1/W2 strict-lower stored transposed in UPPER slots: W(a,b) -> sm[a*128+b] (a>b),
//   tb = L21*W1 stored in the upper-right quadrant: tb(i,c) -> sm[(64+c)*128+i],
//   after inversion the main diagonal is swapped from L_jj to W_jj = 1/L_jj, so
//   W reads unify to sm[a*128+b] for a>=b.
__global__ __launch_bounds__(256, 2) void k_mega(
    const float* __restrict__ yt, const float* __restrict__ yp,
    const float* __restrict__ p_s2e, const float* __restrict__ p_s2b,
    const float* __restrict__ p_len, const float* __restrict__ dm,
    const int* __restrict__ zi, float* ws, float* out)
{
  __shared__ float sm[16384];   // exactly 64 KB
  cg::grid_group grid = cg::this_grid();
  const int tid  = threadIdx.x;
  const int bid  = blockIdx.x;
  const int nbk  = gridDim.x;
  const int gtid = bid*256 + tid;
  const int gsz  = nbk*256;

  float* scal = ws;
  float* t    = ws + 16;
  float* tt   = ws + 16 + QQ;
  float* rv   = ws + 16 + 2*QQ;
  float* xv   = ws + 16 + 3*QQ;
  float* sc   = ws + 16 + 4*QQ;
  int*   cnt  = (int*)(ws + 16 + 5*QQ);
  float* G    = ws + GOFF;

  // ---------- phase 0: per-element stats + bincount ----------
  {
    float s2 = p_s2e[0] + p_s2b[0];
    float a0 = 0.0f, a1 = 0.0f, a2 = 0.0f;
    for (int i = gtid; i < NN; i += gsz) {
      float y  = (yt[i]-yp[i]) / (0.779696801233676f * sqrtf(s2)) + 0.5772156649015329f;
      float em = expf(-y);
      float u  = expf(-em);
      u = fminf(fmaxf(u, 1e-6f), 1.0f - 1e-6f);
      float zs = 1.41421356237309515f * erfinv_f(2.0f*u - 1.0f);
      int q = zi[i];
      atomicAdd(&t[q], zs);
      atomicAdd(&cnt[q], 1);
      a0 += y; a1 += em; a2 += zs*zs;
    }
    a0 = wave_red(a0); a1 = wave_red(a1); a2 = wave_red(a2);
    if ((tid & 63) == 0) {
      atomicAdd(&scal[0], a0);
      atomicAdd(&scal[1], a1);
      atomicAdd(&scal[2], a2);
    }
  }
  grid.sync();

  // ---------- phase 1: make tt / rv / sc ----------
  {
    float a3 = 0.0f;
    for (int q = gtid; q < QQ; q += gsz) {
      int c = cnt[q];
      float scf = sqrtf((float)c);
      float tv = (c > 0) ? t[q]/scf : 0.0f;
      sc[q] = scf; tt[q] = tv; rv[q] = tv;
      a3 += tv*tv;
    }
    a3 = wave_red(a3);
    if ((tid & 63) == 0) atomicAdd(&scal[3], a3);
  }
  grid.sync();

  // ---------- phase 2: build G ----------
  {
    float inv2l = 0.5f / p_len[0];
    float s2b = p_s2b[0], s2e = p_s2e[0];
    for (int idx = gtid; idx < QQ*QQ; idx += gsz) {
      int p = idx >> 11, q = idx & (QQ-1);
      float v = sc[p]*sc[q]*s2b*expf(-dm[(size_t)p*LDM + q]*inv2l);
      if (p == q) v += s2e;
      G[idx] = v;
    }
  }
  grid.sync();

  // ---------- phase 3: blocked Cholesky, 16 stages ----------
  for (int s = 0; s < 16; ++s) {
    const int k0 = s*128;
    const int m  = QQ - k0 - 128;

    // ---- panel: factor 128x128 diag + full in-place inversion -> W to G ----
    if (bid == 0) {
      const int r = tid >> 1, h = tid & 1;
      const int i = r;
      {
        const float* src = &G[(size_t)(k0+r)*QQ + k0];
        for (int j = h; j <= r; j += 2) sm[j*128 + r] = src[j];
      }
      __syncthreads();
      // raw outer-product factorization (identical arithmetic to verified k_factor)
      for (int j = 0; j < 127; ++j) {
        float invd = 1.0f / sm[j*128 + j];
        if (i > j) {
          float ci = sm[j*128 + i] * invd;
          for (int mm = j+1+h; mm <= i; mm += 2) sm[mm*128 + i] -= ci * sm[j*128 + mm];
        }
        __syncthreads();
      }
      // logdet contribution from raw diag: sum log(d_j) == 2*sum log(L_jj)
      if (tid < 128) {
        float lg = logf(sm[tid*128 + tid]);
        lg = wave_red(lg);
        if ((tid & 63) == 0) atomicAdd(&scal[4], lg);
      }
      // scale strict lower to L: L(i,j) = raw/sqrt(d_j)  (raw diag still intact)
      for (int j = h; j < i; j += 2) {
        float dj = sqrtf(sm[j*128 + j]);
        sm[j*128 + i] /= dj;
      }
      __syncthreads();
      if (tid < 128) sm[tid*128 + tid] = sqrtf(sm[tid*128 + tid]);  // L diag
      __syncthreads();
      // invert the two 64x64 diagonal halves; strict lower of W goes to UPPER slots
      if (tid < 128) {
        const int half = tid >> 6, j = tid & 63, off = half << 6;
        float wjj = 1.0f / sm[(off+j)*128 + (off+j)];
        for (int i2 = j+1; i2 < 64; ++i2) {
          float acc = sm[(off+j)*128 + (off+i2)] * wjj;          // m=j term (diag of W)
          for (int mm = j+1; mm < i2; ++mm)
            acc += sm[(off+mm)*128 + (off+i2)] * sm[(off+mm)*128 + (off+j)];
          sm[(off+i2)*128 + (off+j)] = -acc / sm[(off+i2)*128 + (off+i2)];
        }
      }
      __syncthreads();
      // swap diagonal: L_jj -> W_jj = 1/L_jj (exact same value as original k_inv64)
      if (tid < 128) sm[tid*128 + tid] = 1.0f / sm[tid*128 + tid];
      __syncthreads();
      // W21 = -W2 * (L21 * W1); tb into upper-right quadrant slots
      {
        const int ii = tid & 63, jg = tid >> 6;   // 4 groups of 16 cols
        float acc[16];
        #pragma unroll
        for (int a = 0; a < 16; ++a) acc[a] = 0.0f;
        for (int mm = 0; mm < 64; ++mm) {
          float bv = sm[mm*128 + 64 + ii];        // L21(ii, mm)
          #pragma unroll
          for (int a = 0; a < 16; ++a) {
            int c = jg*16 + a;
            float w1v = (mm >= c) ? sm[mm*128 + c] : 0.0f;   // W1(mm,c), diag unified
            acc[a] += bv * w1v;
          }
        }
        #pragma unroll
        for (int a = 0; a < 16; ++a) sm[(64 + jg*16 + a)*128 + ii] = acc[a];  // tb(ii,c)
        __syncthreads();
        #pragma unroll
        for (int a = 0; a < 16; ++a) acc[a] = 0.0f;
        for (int mm = 0; mm <= ii; ++mm) {
          float wv = sm[(64+ii)*128 + 64 + mm];   // W2(ii,mm), diag unified at mm==ii
          #pragma unroll
          for (int a = 0; a < 16; ++a) acc[a] += wv * sm[(64 + jg*16 + a)*128 + mm];
        }
        float* dst = &G[(size_t)(k0+64+ii)*QQ + k0];
        #pragma unroll
        for (int a = 0; a < 16; ++a) dst[jg*16 + a] = -acc[a];  // W21 -> G
      }
      // write W1, W2 (incl diag) to G diag block lower triangle
      for (int idx = tid; idx < 64*64; idx += 256) {
        int a = idx >> 6, b = idx & 63;
        if (b <= a) {
          G[(size_t)(k0+a)*QQ + k0 + b]       = sm[a*128 + b];
          G[(size_t)(k0+64+a)*QQ + k0+64 + b] = sm[(64+a)*128 + 64 + b];
        }
      }
    }
    grid.sync();

    if (m > 0) {
      const int nt = m >> 6;
      // ---- trsm as GEMM: P = A21 * W^T, 64 rows per block ----
      if (bid < nt) {
        float* AT = sm;            // [m][i], 64*68
        float* WT = sm + 64*68;    // [m][j], 64*132, zero above diagonal
        const int rowbase = k0 + 128 + 64*bid;
        const int ty = tid >> 4, tx = tid & 15;
        float acc[4][8];
        #pragma unroll
        for (int a = 0; a < 4; ++a)
          #pragma unroll
          for (int b = 0; b < 8; ++b) acc[a][b] = 0.0f;
        for (int kc = 0; kc < 128; kc += 64) {
          for (int idx = tid; idx < 64*64; idx += 256) {
            int mm = idx & 63, ii = idx >> 6;
            AT[mm*68 + ii] = G[(size_t)(rowbase+ii)*QQ + k0 + kc + mm];
          }
          for (int idx = tid; idx < 64*128; idx += 256) {
            int mm = idx & 63, j = idx >> 6;
            WT[mm*132 + j] = (kc + mm <= j) ? G[(size_t)(k0+j)*QQ + k0 + kc + mm] : 0.0f;
          }
          __syncthreads();
          for (int mm = 0; mm < 64; ++mm) {
            float4 av = *(const float4*)&AT[mm*68 + ty*4];
            float4 b0 = *(const float4*)&WT[mm*132 + tx*8];
            float4 b1 = *(const float4*)&WT[mm*132 + tx*8 + 4];
            float avv[4] = {av.x, av.y, av.z, av.w};
            float bvv[8] = {b0.x, b0.y, b0.z, b0.w, b1.x, b1.y, b1.z, b1.w};
            #pragma unroll
            for (int a = 0; a < 4; ++a)
              #pragma unroll
              for (int b = 0; b < 8; ++b) acc[a][b] += avv[a]*bvv[b];
          }
          __syncthreads();
        }
        #pragma unroll
        for (int a = 0; a < 4; ++a)
          #pragma unroll
          for (int b = 0; b < 8; ++b)
            G[(size_t)(rowbase + ty*4 + a)*QQ + k0 + tx*8 + b] = acc[a][b];
      }
      grid.sync();

      // ---- syrk: trailing C -= P P^T on lower-triangle 64x64 tiles ----
      {
        const int ntri = nt*(nt+1)/2;
        float* PT1 = sm;           // 64*68
        float* PT2 = sm + 64*68;   // 64*68
        const int ty = tid >> 4, tx = tid & 15;
        for (int b = bid; b < ntri; b += nbk) {
          int ti = (int)((sqrtf(8.0f*(float)b + 1.0f) - 1.0f)*0.5f);
          while ((ti+1)*(ti+2)/2 <= b) ++ti;
          while (ti*(ti+1)/2 > b) --ti;
          int tj = b - ti*(ti+1)/2;
          int ibase = k0 + 128 + ti*64, jbase = k0 + 128 + tj*64;
          float acc[4][4];
          #pragma unroll
          for (int a = 0; a < 4; ++a)
            #pragma unroll
            for (int c = 0; c < 4; ++c) acc[a][c] = 0.0f;
          for (int kc = 0; kc < 128; kc += 64) {
            for (int idx = tid; idx < 64*64; idx += 256) {
              int mm = idx & 63, ii = idx >> 6;
              PT1[mm*68 + ii] = G[(size_t)(ibase+ii)*QQ + k0 + kc + mm];
              PT2[mm*68 + ii] = G[(size_t)(jbase+ii)*QQ + k0 + kc + mm];
            }
            __syncthreads();
            for (int mm = 0; mm < 64; ++mm) {
              float4 av = *(const float4*)&PT1[mm*68 + ty*4];
              float4 bv = *(const float4*)&PT2[mm*68 + tx*4];
              float avv[4] = {av.x, av.y, av.z, av.w};
              float bvv[4] = {bv.x, bv.y, bv.z, bv.w};
              #pragma unroll
              for (int a = 0; a < 4; ++a)
                #pragma unroll
                for (int c = 0; c < 4; ++c) acc[a][c] += avv[a]*bvv[c];
            }
            __syncthreads();
          }
          #pragma unroll
          for (int a = 0; a < 4; ++a)
            #pragma unroll
            for (int c = 0; c < 4; ++c)
              G[(size_t)(ibase + ty*4 + a)*QQ + jbase + tx*4 + c] -= acc[a][c];
        }
      }
      grid.sync();
    }
  }

  // ---------- phase 4: forward solve ----------
  for (int s = 0; s < 16; ++s) {
    const int k0 = s*128, m = QQ - k0 - 128;
    if (bid == 0) {
      if (tid < 128) sm[tid] = rv[k0 + tid];
      __syncthreads();
      if (tid < 128) {
        const float* row = &G[(size_t)(k0+tid)*QQ + k0];
        float acc = 0.0f;
        for (int j = 0; j <= tid; ++j) acc += row[j]*sm[j];
        xv[k0+tid] = acc;
      }
    }
    grid.sync();
    if (m > 0) {
      if (tid < 128) sm[tid] = xv[k0 + tid];
      __syncthreads();
      for (int i2 = k0 + 128 + gtid; i2 < QQ; i2 += gsz) {
        const float* row = &G[(size_t)i2*QQ + k0];
        float acc = 0.0f;
        for (int j = 0; j < 128; ++j) acc += row[j]*sm[j];
        rv[i2] -= acc;
      }
      grid.sync();
    }
  }

  // ---------- phase 5: backward solve ----------
  for (int s = 15; s >= 0; --s) {
    const int k0 = s*128;
    if (bid == 0) {
      if (tid < 128) sm[tid] = xv[k0 + tid];
      __syncthreads();
      if (tid < 128) {
        float acc = 0.0f;
        for (int j = tid; j < 128; ++j) acc += G[(size_t)(k0+j)*QQ + k0 + tid]*sm[j];
        xv[k0+tid] = acc;
      }
    }
    grid.sync();
    if (k0 > 0) {
      if (tid < 128) sm[tid] = xv[k0 + tid];
      __syncthreads();
      for (int col = gtid; col < k0; col += gsz) {
        float acc = 0.0f;
        for (int r2 = 0; r2 < 128; ++r2) acc += G[(size_t)(k0+r2)*QQ + col]*sm[r2];
        xv[col] -= acc;
      }
      grid.sync();
    }
  }

  // ---------- phase 6: dot + final ----------
  {
    float a5 = 0.0f;
    for (int q = gtid; q < QQ; q += gsz) a5 += tt[q]*xv[q];
    a5 = wave_red(a5);
    if ((tid & 63) == 0) atomicAdd(&scal[5], a5);
  }
  grid.sync();
  if (bid == 0 && tid == 0) {
    float s2e_ = p_s2e[0], s2b_ = p_s2b[0], s2 = s2e_ + s2b_;
    const float Nf = 4096.0f, Qf = 2048.0f;
    float mld = 2.0f*scal[0] + 2.0f*scal[1] + Nf*logf(s2) + Nf*logf(0.6079271018540267f);
    float quad = (s2/s2e_)*(scal[2] - scal[3] + s2e_*scal[5]);
    float logdetR = Nf*logf(s2e_) - Nf*logf(s2) - Qf*logf(s2e_) + scal[4];
    out[0] = mld + quad - scal[2] + logdetR;
  }
}

// ---------- launch ----------
extern "C" void kernel_launch(void* const* d_in, const int* in_sizes, int n_in,
                              void* d_out, int out_size, void* d_ws, size_t ws_size,
                              hipStream_t stream){
  (void)in_sizes; (void)n_in; (void)out_size; (void)ws_size;
  const float* yt  = (const float*)d_in[0];
  const float* yp  = (const float*)d_in[1];
  const float* s2e = (const float*)d_in[2];
  const float* s2b = (const float*)d_in[3];
  const float* len = (const float*)d_in[4];
  const float* dm  = (const float*)d_in[5];
  const int*   zi  = (const int*)d_in[6];
  float* ws  = (float*)d_ws;
  float* out = (float*)d_out;

  hipMemsetAsync(d_ws, 0, GOFF*sizeof(float), stream);

  // grid = co-resident capacity (cached). 64 KB LDS -> expect 2 blocks/CU -> 512.
  static int g_grid = 0;
  if (g_grid == 0) {
    int bpc = 0;
    if (hipOccupancyMaxActiveBlocksPerMultiprocessor(&bpc, (const void*)k_mega, 256, 0) != hipSuccess || bpc < 1)
      bpc = 1;
    int dev = 0, ncu = 256;
    hipGetDevice(&dev);
    hipDeviceProp_t prop;
    if (hipGetDeviceProperties(&prop, dev) == hipSuccess && prop.multiProcessorCount > 0)
      ncu = prop.multiProcessorCount;
    long g = (long)bpc * (long)ncu;
    if (g > 512) g = 512;
    if (g < 64)  g = 64;   // needs >= nt(=30) blocks for trsm; grid-stride elsewhere
    g_grid = (int)g;
  }

  void* args[] = { (void*)&yt, (void*)&yp, (void*)&s2e, (void*)&s2b, (void*)&len,
                   (void*)&dm, (void*)&zi, (void*)&ws, (void*)&out };
  hipLaunchCooperativeKernel((const void*)k_mega, dim3(g_grid), dim3(256), args, 0, stream);
}

// Round 2
// 3748.407 us; speedup vs baseline: 2.4926x; 2.4926x over previous
//
#include <hip/hip_runtime.h>

#define NN 4096
#define QQ 2048
#define LDM 8192
#define GOFF 16384  // float offset of G inside ws

// ---------- helpers ----------
__device__ __forceinline__ float erfinv_f(float x){
  float w = -logf((1.0f - x)*(1.0f + x));
  float p;
  if (w < 5.0f) {
    w = w - 2.5f;
    p = 2.81022636e-08f;
    p = fmaf(p, w, 3.43273939e-07f);
    p = fmaf(p, w, -3.5233877e-06f);
    p = fmaf(p, w, -4.39150654e-06f);
    p = fmaf(p, w, 0.00021858087f);
    p = fmaf(p, w, -0.00125372503f);
    p = fmaf(p, w, -0.00417768164f);
    p = fmaf(p, w, 0.246640727f);
    p = fmaf(p, w, 1.50140941f);
  } else {
    w = sqrtf(w) - 3.0f;
    p = -0.000200214257f;
    p = fmaf(p, w, 0.000100950558f);
    p = fmaf(p, w, 0.00134934322f);
    p = fmaf(p, w, -0.00367342844f);
    p = fmaf(p, w, 0.00573950773f);
    p = fmaf(p, w, -0.0076224613f);
    p = fmaf(p, w, 0.00943887047f);
    p = fmaf(p, w, 1.00167406f);
    p = fmaf(p, w, 2.83297682f);
  }
  return p * x;
}

__device__ __forceinline__ float wave_red(float v){
  #pragma unroll
  for (int o = 32; o > 0; o >>= 1) v += __shfl_down(v, o, 64);
  return v;
}

// ---------- stage 1: stats + bincount + tt/rv/sc, single block, LDS atomics ----------
__global__ __launch_bounds__(1024) void k_pre(const float* __restrict__ yt, const float* __restrict__ yp,
                                              const float* __restrict__ p_s2e, const float* __restrict__ p_s2b,
                                              const int* __restrict__ zi, float* __restrict__ ws){
  __shared__ float t_s[QQ];
  __shared__ int   c_s[QQ];
  __shared__ float red[48];
  float* scal = ws;
  float* tt   = ws + 16 + QQ;
  float* rv   = ws + 16 + 2*QQ;
  float* sc   = ws + 16 + 4*QQ;
  const int tid = threadIdx.x;
  for (int q = tid; q < QQ; q += 1024){ t_s[q] = 0.0f; c_s[q] = 0; }
  __syncthreads();
  const float s2  = p_s2e[0] + p_s2b[0];
  const float den = 0.779696801233676f * sqrtf(s2);
  float a0 = 0.0f, a1 = 0.0f, a2 = 0.0f;
  for (int i = tid; i < NN; i += 1024){
    float y  = (yt[i]-yp[i]) / den + 0.5772156649015329f;
    float em = expf(-y);
    float u  = expf(-em);
    u = fminf(fmaxf(u, 1e-6f), 1.0f - 1e-6f);
    float zs = 1.41421356237309515f * erfinv_f(2.0f*u - 1.0f);
    int q = zi[i];
    atomicAdd(&t_s[q], zs);
    atomicAdd(&c_s[q], 1);
    a0 += y; a1 += em; a2 += zs*zs;
  }
  a0 = wave_red(a0); a1 = wave_red(a1); a2 = wave_red(a2);
  const int wid = tid >> 6;
  if ((tid & 63) == 0){ red[wid] = a0; red[16+wid] = a1; red[32+wid] = a2; }
  __syncthreads();
  if (tid == 0){
    float x0=0,x1=0,x2=0;
    for (int w = 0; w < 16; ++w){ x0 += red[w]; x1 += red[16+w]; x2 += red[32+w]; }
    scal[0] = x0; scal[1] = x1; scal[2] = x2; scal[4] = 0.0f;  // scal[4] accumulated by k_panel
  }
  float a3 = 0.0f;
  for (int q = tid; q < QQ; q += 1024){
    int c = c_s[q];
    float scf = sqrtf((float)c);
    float tv = (c > 0) ? t_s[q]/scf : 0.0f;
    sc[q] = scf; tt[q] = tv; rv[q] = tv;
    a3 += tv*tv;
  }
  a3 = wave_red(a3);
  __syncthreads();
  if ((tid & 63) == 0) red[wid] = a3;
  __syncthreads();
  if (tid == 0){
    float x3 = 0; for (int w = 0; w < 16; ++w) x3 += red[w];
    scal[3] = x3;
  }
}

// ---------- stage 2: build G, float4-vectorized ----------
__global__ __launch_bounds__(256) void k_build_G(const float* __restrict__ dm, const float* __restrict__ sc,
                                                 const float* __restrict__ p_s2e, const float* __restrict__ p_s2b,
                                                 const float* __restrict__ p_len, float* __restrict__ G){
  const int idx = blockIdx.x*256 + threadIdx.x;          // 0 .. 2048*512-1
  const int p  = idx >> 9;
  const int q4 = (idx & 511) << 2;
  const float inv2l = 0.5f / p_len[0];
  const float s2b = p_s2b[0], s2e = p_s2e[0];
  const float scp = sc[p];
  const float4 d4 = *(const float4*)&dm[(size_t)p*LDM + q4];
  const float4 s4 = *(const float4*)&sc[q4];
  float vv[4] = { scp*s4.x*s2b*expf(-d4.x*inv2l),
                  scp*s4.y*s2b*expf(-d4.y*inv2l),
                  scp*s4.z*s2b*expf(-d4.z*inv2l),
                  scp*s4.w*s2b*expf(-d4.w*inv2l) };
  #pragma unroll
  for (int k = 0; k < 4; ++k) if (p == q4 + k) vv[k] += s2e;
  float4 o; o.x = vv[0]; o.y = vv[1]; o.z = vv[2]; o.w = vv[3];
  *(float4*)&G[(size_t)p*QQ + q4] = o;
}

// ---------- stage 3 panel: stripe-blocked factor + logdet + inv64 + w21, one launch ----------
// LDS col-major: elem(i,j) = s[j*128+i], lower (i>=j) holds A/L; upper slots hold W transposed
// (W(a,b) at s[a*128+b], a>b), tb in upper-right quadrant, diag swapped to W after inversion.
__global__ __launch_bounds__(512) void k_panel(float* __restrict__ G, float* __restrict__ scal, int k0){
  __shared__ float s[128*128];   // 64 KB
  const int tid = threadIdx.x;
  {
    const int r = tid >> 2, h = tid & 3;
    const float* src = &G[(size_t)(k0+r)*QQ + k0];
    for (int j = h; j <= r; j += 4) s[j*128 + r] = src[j];
  }
  __syncthreads();
  float lacc = 0.0f;
  const int i0 = tid & 127, m0 = tid >> 7;   // row ownership + column-phase
  for (int cb = 0; cb < 4; ++cb){
    const int c0 = cb*32;
    // raw right-looking factor restricted to the 32-wide stripe
    for (int j = c0; j < c0+31; ++j){
      const float invd = 1.0f / s[j*128 + j];
      if (i0 > j){
        const float ci = s[j*128 + i0] * invd;
        const int mmax = (i0 < c0+31) ? i0 : (c0+31);
        for (int mm = j+1+m0; mm <= mmax; mm += 4)
          s[mm*128 + i0] -= ci * s[j*128 + mm];
      }
      __syncthreads();
    }
    // logdet from raw diag (sum log d_j == 2*sum log L_jj), then scale stripe to proper L
    if (tid >= c0 && tid < c0+32) lacc += logf(s[tid*128 + tid]);
    for (int e = tid; e < 32*128; e += 512){
      const int j = c0 + (e >> 7);
      const int i = e & 127;
      if (i > j) s[j*128 + i] /= sqrtf(s[j*128 + j]);
    }
    __syncthreads();
    if (tid >= c0 && tid < c0+32) s[tid*128 + tid] = sqrtf(s[tid*128 + tid]);
    __syncthreads();
    // rank-32 trailing update on remaining columns (proper form, no divides)
    if (cb < 3){
      const int t0 = c0 + 32;
      if (i0 >= t0){
        float li[32];
        #pragma unroll
        for (int j = 0; j < 32; ++j) li[j] = s[(c0+j)*128 + i0];
        for (int mm = t0 + m0; mm <= i0; mm += 4){
          float acc = s[mm*128 + i0];
          #pragma unroll
          for (int j = 0; j < 32; ++j) acc -= li[j] * s[(c0+j)*128 + mm];
          s[mm*128 + i0] = acc;
        }
      }
      __syncthreads();
    }
  }
  // logdet reduce -> scal[4]
  lacc = wave_red(lacc);
  if ((tid & 63) == 0) atomicAdd(&scal[4], lacc);
  // invert the two 64x64 diagonal blocks of L (strict lower of W into upper slots)
  if (tid < 128){
    const int j = tid & 63, off = (tid >> 6) << 6;
    const float wjj = 1.0f / s[(off+j)*128 + (off+j)];
    for (int i2 = j+1; i2 < 64; ++i2){
      float acc = s[(off+j)*128 + (off+i2)] * wjj;
      for (int mm = j+1; mm < i2; ++mm)
        acc += s[(off+mm)*128 + (off+i2)] * s[(off+mm)*128 + (off+j)];
      s[(off+i2)*128 + (off+j)] = -acc / s[(off+i2)*128 + (off+i2)];
    }
  }
  __syncthreads();
  if (tid < 128) s[tid*128 + tid] = 1.0f / s[tid*128 + tid];   // diag -> W_jj
  __syncthreads();
  // W21 = -W2 * (L21 * W1); tb in upper-right quadrant; write W21 to G
  {
    const int ii = tid & 63, jg = tid >> 6;   // 8 groups x 8 columns
    float acc[8];
    #pragma unroll
    for (int a = 0; a < 8; ++a) acc[a] = 0.0f;
    for (int mm = 0; mm < 64; ++mm){
      const float bv = s[mm*128 + 64 + ii];               // L21(ii,mm)
      #pragma unroll
      for (int a = 0; a < 8; ++a){
        const int c = jg*8 + a;
        const float w1v = (mm >= c) ? s[mm*128 + c] : 0.0f;  // W1(mm,c)
        acc[a] += bv * w1v;
      }
    }
    #pragma unroll
    for (int a = 0; a < 8; ++a) s[(64 + jg*8 + a)*128 + ii] = acc[a];   // tb(ii,c)
    __syncthreads();
    #pragma unroll
    for (int a = 0; a < 8; ++a) acc[a] = 0.0f;
    for (int mm = 0; mm <= ii; ++mm){
      const float wv = s[(64+ii)*128 + 64 + mm];          // W2(ii,mm)
      #pragma unroll
      for (int a = 0; a < 8; ++a) acc[a] += wv * s[(64 + jg*8 + a)*128 + mm];
    }
    float* dst = &G[(size_t)(k0+64+ii)*QQ + k0];
    #pragma unroll
    for (int a = 0; a < 8; ++a) dst[jg*8 + a] = -acc[a];
  }
  // write W1, W2 lower triangles to G
  for (int idx = tid; idx < 64*64; idx += 512){
    const int a = idx >> 6, b = idx & 63;
    if (b <= a){
      G[(size_t)(k0+a)*QQ + k0 + b]       = s[a*128 + b];
      G[(size_t)(k0+64+a)*QQ + k0+64 + b] = s[(64+a)*128 + 64 + b];
    }
  }
}

// panel "TRSM" as GEMM: P = A21 * W^T (verbatim from verified baseline)
__global__ __launch_bounds__(256) void k_trsm(float* G, int k0){
  __shared__ alignas(16) float AT[64*68];    // [m][i]
  __shared__ alignas(16) float WT[64*132];   // [m][j], zero-filled above diagonal
  int tid = threadIdx.x;
  int rowbase = k0 + 128 + 64*(int)blockIdx.x;
  int ty = tid >> 4, tx = tid & 15;
  float acc[4][8];
  #pragma unroll
  for (int a = 0; a < 4; ++a)
    #pragma unroll
    for (int b = 0; b < 8; ++b) acc[a][b] = 0.0f;
  for (int kc = 0; kc < 128; kc += 64) {
    for (int idx = tid; idx < 64*64; idx += 256) {
      int m = idx & 63, ii = idx >> 6;
      AT[m*68 + ii] = G[(size_t)(rowbase+ii)*QQ + k0 + kc + m];
    }
    for (int idx = tid; idx < 64*128; idx += 256) {
      int m = idx & 63, j = idx >> 6;
      WT[m*132 + j] = (kc + m <= j) ? G[(size_t)(k0+j)*QQ + k0 + kc + m] : 0.0f;
    }
    __syncthreads();
    for (int m = 0; m < 64; ++m) {
      float4 av = *(const float4*)&AT[m*68 + ty*4];
      float4 b0 = *(const float4*)&WT[m*132 + tx*8];
      float4 b1 = *(const float4*)&WT[m*132 + tx*8 + 4];
      float avv[4] = {av.x, av.y, av.z, av.w};
      float bvv[8] = {b0.x, b0.y, b0.z, b0.w, b1.x, b1.y, b1.z, b1.w};
      #pragma unroll
      for (int a = 0; a < 4; ++a)
        #pragma unroll
        for (int b = 0; b < 8; ++b) acc[a][b] += avv[a]*bvv[b];
    }
    __syncthreads();
  }
  #pragma unroll
  for (int a = 0; a < 4; ++a)
    #pragma unroll
    for (int b = 0; b < 8; ++b)
      G[(size_t)(rowbase + ty*4 + a)*QQ + k0 + tx*8 + b] = acc[a][b];
}

// trailing update: C -= P P^T on lower-triangle 64x64 tiles (verbatim from baseline)
__global__ __launch_bounds__(256) void k_syrk(float* G, int k0){
  __shared__ alignas(16) float PT1[64*68];
  __shared__ alignas(16) float PT2[64*68];
  int b = blockIdx.x;
  int ti = (int)((sqrtf(8.0f*(float)b + 1.0f) - 1.0f)*0.5f);
  while ((ti+1)*(ti+2)/2 <= b) ++ti;
  while (ti*(ti+1)/2 > b) --ti;
  int tj = b - ti*(ti+1)/2;
  int ibase = k0 + 128 + ti*64, jbase = k0 + 128 + tj*64;
  int tid = threadIdx.x, ty = tid >> 4, tx = tid & 15;
  float acc[4][4];
  #pragma unroll
  for (int a = 0; a < 4; ++a)
    #pragma unroll
    for (int c = 0; c < 4; ++c) acc[a][c] = 0.0f;
  for (int kc = 0; kc < 128; kc += 64) {
    for (int idx = tid; idx < 64*64; idx += 256) {
      int m = idx & 63, ii = idx >> 6;
      PT1[m*68 + ii] = G[(size_t)(ibase+ii)*QQ + k0 + kc + m];
      PT2[m*68 + ii] = G[(size_t)(jbase+ii)*QQ + k0 + kc + m];
    }
    __syncthreads();
    for (int m = 0; m < 64; ++m) {
      float4 av = *(const float4*)&PT1[m*68 + ty*4];
      float4 bv = *(const float4*)&PT2[m*68 + tx*4];
      float avv[4] = {av.x, av.y, av.z, av.w};
      float bvv[4] = {bv.x, bv.y, bv.z, bv.w};
      #pragma unroll
      for (int a = 0; a < 4; ++a)
        #pragma unroll
        for (int c = 0; c < 4; ++c) acc[a][c] += avv[a]*bvv[c];
    }
    __syncthreads();
  }
  #pragma unroll
  for (int a = 0; a < 4; ++a)
    #pragma unroll
    for (int c = 0; c < 4; ++c)
      G[(size_t)(ibase + ty*4 + a)*QQ + jbase + tx*4 + c] -= acc[a][c];
}

// ---------- stage 4: ALL solves + dot + final in one single-block launch ----------
__global__ __launch_bounds__(1024) void k_solve(const float* __restrict__ G, float* __restrict__ ws,
                                                const float* __restrict__ p_s2e, const float* __restrict__ p_s2b,
                                                float* __restrict__ out){
  __shared__ float sx[128], sy[128], red[16];
  float* scal = ws;
  float* tt   = ws + 16 + QQ;
  float* rv   = ws + 16 + 2*QQ;
  float* xv   = ws + 16 + 3*QQ;
  const int tid = threadIdx.x;
  // forward
  for (int s = 0; s < 16; ++s){
    const int k0 = s*128;
    if (tid < 128) sx[tid] = rv[k0 + tid];
    __syncthreads();
    if (tid < 128){
      const float* row = &G[(size_t)(k0+tid)*QQ + k0];
      float acc = 0.0f;
      for (int j = 0; j <= tid; ++j) acc += row[j]*sx[j];
      sy[tid] = acc; xv[k0+tid] = acc;
    }
    __syncthreads();
    const int m = QQ - k0 - 128;
    if (m > 0){
      const int lane = tid & 15, rg = tid >> 4;   // 16 lanes per row, coalesced 64B chunks
      for (int r = rg; r < m; r += 64){
        const float* row = &G[(size_t)(k0+128+r)*QQ + k0];
        float acc = 0.0f;
        #pragma unroll
        for (int j = lane; j < 128; j += 16) acc += row[j]*sy[j];
        #pragma unroll
        for (int o = 8; o > 0; o >>= 1) acc += __shfl_down(acc, o, 16);
        if (lane == 0) rv[k0+128+r] -= acc;
      }
      __syncthreads();
    }
  }
  // backward
  for (int s = 15; s >= 0; --s){
    const int k0 = s*128;
    if (tid < 128) sx[tid] = xv[k0 + tid];
    __syncthreads();
    if (tid < 128){
      float acc = 0.0f;
      for (int j = tid; j < 128; ++j) acc += G[(size_t)(k0+j)*QQ + k0 + tid]*sx[j];
      sy[tid] = acc; xv[k0+tid] = acc;
    }
    __syncthreads();
    if (k0 > 0){
      for (int c = tid; c < k0; c += 1024){   // thread-per-column: coalesced
        float acc = 0.0f;
        for (int r = 0; r < 128; ++r) acc += G[(size_t)(k0+r)*QQ + c]*sy[r];
        xv[c] -= acc;
      }
      __syncthreads();
    }
  }
  // dot + final
  float a5 = 0.0f;
  for (int q = tid; q < QQ; q += 1024) a5 += tt[q]*xv[q];
  a5 = wave_red(a5);
  if ((tid & 63) == 0) red[tid >> 6] = a5;
  __syncthreads();
  if (tid == 0){
    float dot = 0.0f;
    #pragma unroll
    for (int w = 0; w < 16; ++w) dot += red[w];
    const float s2e_ = p_s2e[0], s2b_ = p_s2b[0], s2 = s2e_ + s2b_;
    const float Nf = 4096.0f, Qf = 2048.0f;
    const float mld = 2.0f*scal[0] + 2.0f*scal[1] + Nf*logf(s2) + Nf*logf(0.6079271018540267f);
    const float quad = (s2/s2e_)*(scal[2] - scal[3] + s2e_*dot);
    const float logdetR = Nf*logf(s2e_) - Nf*logf(s2) - Qf*logf(s2e_) + scal[4];
    out[0] = mld + quad - scal[2] + logdetR;
  }
}

// ---------- launch ----------
extern "C" void kernel_launch(void* const* d_in, const int* in_sizes, int n_in,
                              void* d_out, int out_size, void* d_ws, size_t ws_size,
                              hipStream_t stream){
  (void)in_sizes; (void)n_in; (void)out_size; (void)ws_size;
  const float* yt  = (const float*)d_in[0];
  const float* yp  = (const float*)d_in[1];
  const float* s2e = (const float*)d_in[2];
  const float* s2b = (const float*)d_in[3];
  const float* len = (const float*)d_in[4];
  const float* dm  = (const float*)d_in[5];
  const int*   zi  = (const int*)d_in[6];
  float* ws  = (float*)d_ws;
  float* sc  = ws + 16 + 4*QQ;
  float* G   = ws + GOFF;
  float* out = (float*)d_out;

  // no memset: k_pre writes scal[0..4]; t/cnt live in LDS; build_G fully writes G.
  k_pre    <<<1, 1024, 0, stream>>>(yt, yp, s2e, s2b, zi, ws);
  k_build_G<<<4096, 256, 0, stream>>>(dm, sc, s2e, s2b, len, G);

  for (int s = 0; s < 16; ++s) {
    const int k0 = s*128, m = QQ - k0 - 128;
    k_panel<<<1, 512, 0, stream>>>(G, ws, k0);
    if (m > 0) {
      const int nt = m/64;
      k_trsm<<<nt, 256, 0, stream>>>(G, k0);
      k_syrk<<<nt*(nt+1)/2, 256, 0, stream>>>(G, k0);
    }
  }
  k_solve<<<1, 1024, 0, stream>>>(G, ws, s2e, s2b, out);
}